// Round 11
// baseline (144.699 us; speedup 1.0000x reference)
//
#include <hip/hip_runtime.h>
#include <hip/hip_fp16.h>
#include <math.h>

#define A_NUM 360
#define DET_N 448
#define NN 320
#define NSAMP 452
#define NB 2
#define NPIX (NN * NN)
#define NRAY (A_NUM * DET_N)
#define NCH 4
#define CHS (NSAMP / NCH)   // 113
#define NORB 25600          // 160*160 rotation orbits
#define NSPQ15 15           // bp4 angle splits (90/15=6 even; ws-proven tier)
#define NSPQ12 12           // mid tier
#define PN 324              // padded dim (+2 each side)

// R = 320*sqrt(2)/2, DT = 2R/452, t0 = 500 - R + 0.5*DT
#define R_D   226.27416997969522
#define DT_D  (2.0 * R_D / (double)NSAMP)
#define T0_D  (500.0 - R_D + 0.5 * DT_D)
#define DTF   ((float)DT_D)
#define T0F   ((float)T0_D)
#define INVDT ((float)(1.0 / DT_D))
#define K0F   ((float)((-1.4150 - T0_D) * (1.0 / DT_D)))

typedef float f32x2 __attribute__((ext_vector_type(2)));

// tile swizzle: orbit index <-> (ri,rj) with 8x8 tiles (20x20 tile grid).
// wave (64 lanes) = one 8x8 pixel tile (round-5 proven, 92->77us).
__device__ __forceinline__ int orb_swizzle(int ri, int rj) {
    int tile = (rj >> 3) * 20 + (ri >> 3);
    int intra = ((rj & 7) << 3) | (ri & 7);
    return (tile << 6) | intra;
}

// ---------------------------------------------------------------------------
// prep: tabD[ray]=(dirx,diry); tabS[a]=(cb,sb, padded srcx, padded srcy);
//       dirq[am<90][d]=(dirx,diry,DT*dirx,DT*diry)  (float4 restored — r10's
//       float2 compaction traded LDS for VALU and lost);
//       angG[a]=(cb,sb, srcx+159.5, srcy+159.5)
// ---------------------------------------------------------------------------
__global__ __launch_bounds__(256) void prep_k(float2* __restrict__ tabD,
                                              float4* __restrict__ tabS,
                                              float4* __restrict__ dirq,
                                              float4* __restrict__ angG) {
    int tid = blockIdx.x * blockDim.x + threadIdx.x;
    if (tid >= NRAY) return;
    int d = tid % DET_N, a = tid / DET_N;
    double beta = (double)a * (M_PI / 180.0);
    double cbd = cos(beta), sbd = sin(beta);
    double u = ((double)d - 223.5) * 1.6;
    double inorm = 1.0 / sqrt(1.0e6 + u * u);
    float dx = (float)((-1000.0 * cbd - u * sbd) * inorm);
    float dy = (float)((-1000.0 * sbd + u * cbd) * inorm);
    tabD[tid] = make_float2(dx, dy);
    if (d == 0) {
        tabS[a] = make_float4((float)cbd, (float)sbd,
                              (float)(500.0 * cbd + 161.5),   // +2 pad
                              (float)(500.0 * sbd + 161.5));  // +2 pad
        angG[a] = make_float4((float)cbd, (float)sbd,
                              (float)(500.0 * cbd + 159.5),
                              (float)(500.0 * sbd + 159.5));
    }
    if (a < 90) dirq[a * DET_N + d] = make_float4(dx, dy, DTF * dx, DTF * dy);
}

// pack (batch0, batch1) at pixel idx as fp16 pair (b0 low, b1 high); 0 if invalid
__device__ __forceinline__ unsigned packpix(const float* __restrict__ x,
                                            bool v, int idx) {
    if (!v) return 0u;
    __half2 h = __floats2half2_rn(x[idx], x[NPIX + idx]);
    return *reinterpret_cast<unsigned*>(&h);
}
__device__ __forceinline__ f32x2 up16(unsigned w) {
    __half2 h = *reinterpret_cast<__half2*>(&w);
    return (f32x2){__low2float(h), __high2float(h)};
}

// fp16-quad row-major: cell t=(py*PN+px), words = pixels (x0,y0),(x0+1,y0),
// (x0,y0+1),(x0+1,y0+1) in orig coords (pad shift -2).
__global__ __launch_bounds__(256) void interleaveQB_k(const float* __restrict__ x,
                                                      uint4* __restrict__ xb) {
    int t = blockIdx.x * blockDim.x + threadIdx.x;
    if (t >= PN * PN) return;
    int px = t % PN, py = t / PN;
    int ox = px - 2, oy = py - 2;
    bool cx0 = (ox >= 0) && (ox < NN);
    bool cx1 = (ox + 1 >= 0) && (ox + 1 < NN);
    bool cy0 = (oy >= 0) && (oy < NN);
    bool cy1 = (oy + 1 >= 0) && (oy + 1 < NN);
    int b = oy * NN + ox;
    uint4 w;
    w.x = packpix(x, cx0 && cy0, b);
    w.y = packpix(x, cx1 && cy0, b + 1);
    w.z = packpix(x, cx0 && cy1, b + NN);
    w.w = packpix(x, cx1 && cy1, b + NN + 1);
    xb[t] = w;
}

// fp16-quad transposed: t: r=t%PN (ps-x = orig row), q=t/PN (ps-y = orig col)
__global__ __launch_bounds__(256) void interleaveQBT_k(const float* __restrict__ x,
                                                       uint4* __restrict__ xbT) {
    int t = blockIdx.x * blockDim.x + threadIdx.x;
    if (t >= PN * PN) return;
    int r = t % PN, q = t / PN;
    int row0 = r - 2, col0 = q - 2;
    bool r0v = (row0 >= 0) && (row0 < NN);
    bool r1v = (row0 + 1 >= 0) && (row0 + 1 < NN);
    bool c0v = (col0 >= 0) && (col0 < NN);
    bool c1v = (col0 + 1 >= 0) && (col0 + 1 < NN);
    int b = row0 * NN + col0;
    uint4 w;
    w.x = packpix(x, r0v && c0v, b);
    w.y = packpix(x, r1v && c0v, b + NN);
    w.z = packpix(x, r0v && c1v, b + 1);
    w.w = packpix(x, r1v && c1v, b + NN + 1);
    xbT[t] = w;
}

// ---------------------------------------------------------------------------
// partial forward projection (round-10: slab skip + wave-tile swizzle +
// explicit 2-deep software pipeline).
// ---------------------------------------------------------------------------
__device__ __forceinline__ void samp1(const uint4* __restrict__ buf,
                                      float ix, float iy,
                                      f32x2& accA, f32x2& accB) {
    float xf = floorf(ix), yf = floorf(iy);
    float fx = ix - xf, fy = iy - yf;
    int idx = (int)yf * PN + (int)xf;
    uint4 qv = buf[idx];
    float gx = 1.0f - fx, gy = 1.0f - fy;
    float w00 = gx * gy, w01 = fx * gy, w10 = gx * fy, w11 = fx * fy;
    accA = __builtin_elementwise_fma((f32x2){w00, w00}, up16(qv.x), accA);
    accB = __builtin_elementwise_fma((f32x2){w01, w01}, up16(qv.y), accB);
    accA = __builtin_elementwise_fma((f32x2){w10, w10}, up16(qv.z), accA);
    accB = __builtin_elementwise_fma((f32x2){w11, w11}, up16(qv.w), accB);
}

#define PLOAD(Q0, Q1, Q2, Q3, FX, FY)                                  \
    {                                                                  \
        float x0_ = lx,               y0_ = ly;                        \
        float x1_ = lx + stx,         y1_ = ly + sty;                  \
        float x2_ = lx + 2.0f * stx,  y2_ = ly + 2.0f * sty;           \
        float x3_ = lx + 3.0f * stx,  y3_ = ly + 3.0f * sty;           \
        float xf0_ = floorf(x0_), yf0_ = floorf(y0_);                  \
        float xf1_ = floorf(x1_), yf1_ = floorf(y1_);                  \
        float xf2_ = floorf(x2_), yf2_ = floorf(y2_);                  \
        float xf3_ = floorf(x3_), yf3_ = floorf(y3_);                  \
        Q0 = buf[(int)yf0_ * PN + (int)xf0_];                          \
        Q1 = buf[(int)yf1_ * PN + (int)xf1_];                          \
        Q2 = buf[(int)yf2_ * PN + (int)xf2_];                          \
        Q3 = buf[(int)yf3_ * PN + (int)xf3_];                          \
        FX##0 = x0_ - xf0_; FY##0 = y0_ - yf0_;                        \
        FX##1 = x1_ - xf1_; FY##1 = y1_ - yf1_;                        \
        FX##2 = x2_ - xf2_; FY##2 = y2_ - yf2_;                        \
        FX##3 = x3_ - xf3_; FY##3 = y3_ - yf3_;                        \
        lx += 4.0f * stx; ly += 4.0f * sty;                            \
    }

#define PCONS(Q0, Q1, Q2, Q3, FX, FY)                                  \
    {                                                                  \
        float gx0_ = 1.0f - FX##0, gy0_ = 1.0f - FY##0;                \
        float gx1_ = 1.0f - FX##1, gy1_ = 1.0f - FY##1;                \
        float gx2_ = 1.0f - FX##2, gy2_ = 1.0f - FY##2;                \
        float gx3_ = 1.0f - FX##3, gy3_ = 1.0f - FY##3;                \
        float w_;                                                      \
        w_ = gx0_ * gy0_;  accA = __builtin_elementwise_fma((f32x2){w_, w_}, up16(Q0.x), accA); \
        w_ = FX##0 * gy0_; accB = __builtin_elementwise_fma((f32x2){w_, w_}, up16(Q0.y), accB); \
        w_ = gx0_ * FY##0; accA = __builtin_elementwise_fma((f32x2){w_, w_}, up16(Q0.z), accA); \
        w_ = FX##0 * FY##0;accB = __builtin_elementwise_fma((f32x2){w_, w_}, up16(Q0.w), accB); \
        w_ = gx1_ * gy1_;  accA = __builtin_elementwise_fma((f32x2){w_, w_}, up16(Q1.x), accA); \
        w_ = FX##1 * gy1_; accB = __builtin_elementwise_fma((f32x2){w_, w_}, up16(Q1.y), accB); \
        w_ = gx1_ * FY##1; accA = __builtin_elementwise_fma((f32x2){w_, w_}, up16(Q1.z), accA); \
        w_ = FX##1 * FY##1;accB = __builtin_elementwise_fma((f32x2){w_, w_}, up16(Q1.w), accB); \
        w_ = gx2_ * gy2_;  accA = __builtin_elementwise_fma((f32x2){w_, w_}, up16(Q2.x), accA); \
        w_ = FX##2 * gy2_; accB = __builtin_elementwise_fma((f32x2){w_, w_}, up16(Q2.y), accB); \
        w_ = gx2_ * FY##2; accA = __builtin_elementwise_fma((f32x2){w_, w_}, up16(Q2.z), accA); \
        w_ = FX##2 * FY##2;accB = __builtin_elementwise_fma((f32x2){w_, w_}, up16(Q2.w), accB); \
        w_ = gx3_ * gy3_;  accA = __builtin_elementwise_fma((f32x2){w_, w_}, up16(Q3.x), accA); \
        w_ = FX##3 * gy3_; accB = __builtin_elementwise_fma((f32x2){w_, w_}, up16(Q3.y), accB); \
        w_ = gx3_ * FY##3; accA = __builtin_elementwise_fma((f32x2){w_, w_}, up16(Q3.z), accA); \
        w_ = FX##3 * FY##3;accB = __builtin_elementwise_fma((f32x2){w_, w_}, up16(Q3.w), accB); \
    }

__global__ __launch_bounds__(256) void partial_k(const float2* __restrict__ tabD,
                                                 const float4* __restrict__ tabS,
                                                 const uint4* __restrict__ bufR,
                                                 const uint4* __restrict__ bufT,
                                                 float2* __restrict__ part) {
    int tid = blockIdx.x * blockDim.x + threadIdx.x;
    if (tid >= NRAY * NCH) return;
    // wave-tile swizzle: lane = d_lo(4b) | c(2b); upper bits = (a, d_hi)
    int d_lo = tid & 15;
    int c    = (tid >> 4) & 3;
    int rest = tid >> 6;            // [0, 360*28)
    int d_hi = rest % (DET_N / 16); // 28 det-groups
    int a    = rest / (DET_N / 16);
    int ray  = a * DET_N + d_hi * 16 + d_lo;

    float2 D = tabD[ray];
    float4 S = tabS[a];
    bool swp = fabsf(S.x) > fabsf(S.y);
    float dirx = swp ? D.y : D.x;
    float diry = swp ? D.x : D.y;
    float sx   = swp ? S.w : S.z;
    float sy   = swp ? S.z : S.w;
    const uint4* __restrict__ buf = swp ? bufT : bufR;

    // slab intersection: t-range where ix,iy both in [0.5, 322.5]
    float invx = __builtin_amdgcn_rcpf(dirx);
    float invy = __builtin_amdgcn_rcpf(diry);
    float tx1 = (0.5f   - sx) * invx;
    float tx2 = (322.5f - sx) * invx;
    float ty1 = (0.5f   - sy) * invy;
    float ty2 = (322.5f - sy) * invy;
    float tmn = fmaxf(fminf(tx1, tx2), fminf(ty1, ty2));
    float tmx = fminf(fmaxf(tx1, tx2), fmaxf(ty1, ty2));
    float smnf = fminf(fmaxf(ceilf((tmn - T0F) * INVDT), 0.0f), (float)(NSAMP - 1));
    float smxf = fminf(fmaxf(floorf((tmx - T0F) * INVDT), 0.0f), (float)(NSAMP - 1));
    int smin = (int)smnf;
    int smax = (int)smxf;
    // this chunk covers samples s = c + 4k, k in [0, CHS)
    int klo = (smin - c + 3) >> 2;  if (klo < 0) klo = 0;
    int khi = (smax - c) >> 2;      if (khi > CHS - 1) khi = CHS - 1;
    int kn = khi - klo + 1;
    if (kn < 0) kn = 0;

    float t0c = fmaf((float)(c + 4 * klo), DTF, T0F);
    float lx = fmaf(t0c, dirx, sx);
    float ly = fmaf(t0c, diry, sy);
    float stx = (4.0f * DTF) * dirx;
    float sty = (4.0f * DTF) * diry;

    f32x2 accA = {0.0f, 0.0f}, accB = {0.0f, 0.0f};

    int nblk = kn >> 2;
    int rem  = kn & 3;

    uint4 qa0, qa1, qa2, qa3, qb0, qb1, qb2, qb3;
    float fxa0, fxa1, fxa2, fxa3, fya0, fya1, fya2, fya3;
    float fxb0, fxb1, fxb2, fxb3, fyb0, fyb1, fyb2, fyb3;

    if (nblk > 0) {
        PLOAD(qa0, qa1, qa2, qa3, fxa, fya)
        int b = 1;
        for (; b + 1 < nblk; b += 2) {
            PLOAD(qb0, qb1, qb2, qb3, fxb, fyb)
            PCONS(qa0, qa1, qa2, qa3, fxa, fya)
            PLOAD(qa0, qa1, qa2, qa3, fxa, fya)
            PCONS(qb0, qb1, qb2, qb3, fxb, fyb)
        }
        if (b < nblk) {
            PLOAD(qb0, qb1, qb2, qb3, fxb, fyb)
            PCONS(qa0, qa1, qa2, qa3, fxa, fya)
            PCONS(qb0, qb1, qb2, qb3, fxb, fyb)
        } else {
            PCONS(qa0, qa1, qa2, qa3, fxa, fya)
        }
    }
    for (int r = 0; r < rem; ++r) {
        samp1(buf, lx, ly, accA, accB);
        lx += stx; ly += sty;
    }

    f32x2 acc = accA + accB;
    part[c * NRAY + ray] = make_float2(acc.x, acc.y);
}

// ---------------------------------------------------------------------------
// finalize4: reduce chunk partials (fixed order), pack rv rotation-quads
// ---------------------------------------------------------------------------
__global__ __launch_bounds__(256) void finalize4_k(const float* __restrict__ p,
                                                   const float2* __restrict__ part,
                                                   float4* __restrict__ rvq) {
    int tid = blockIdx.x * blockDim.x + threadIdx.x;
    if (tid >= 90 * DET_N) return;
    int d = tid % DET_N, am = tid / DET_N;
    float rv[8];
#pragma unroll
    for (int k = 0; k < 4; ++k) {
        int ray = (am + 90 * k) * DET_N + d;
        float a0 = 0.0f, a1 = 0.0f;
#pragma unroll
        for (int c = 0; c < NCH; ++c) {
            float2 pr = part[c * NRAY + ray];
            a0 += pr.x; a1 += pr.y;
        }
        rv[2 * k]     = -fmaf(a0, DTF, -p[ray]) * DTF;
        rv[2 * k + 1] = -fmaf(a1, DTF, -p[NRAY + ray]) * DTF;
    }
    rvq[2 * tid]     = make_float4(rv[0], rv[1], rv[2], rv[3]);
    rvq[2 * tid + 1] = make_float4(rv[4], rv[5], rv[6], rv[7]);
}

// ---------------------------------------------------------------------------
// bp4: 4-fold rotation symmetric adjoint.
// Round 11: bp4 is VALU+lgkmcnt bound (r10's LDS-traffic cut with +2 VALU/det
// LOST -> not LDS-pipe-bound). Fix the per-detector serialization: 2-det
// unroll of the LDS tap loop — 6 ds_reads issued together, ONE lgkmcnt wait
// per pair, then 2x34 VALU. sD restored to float4 (r9 math, bit-proven).
// Accumulation stays ascending-d per lane -> bit-identical.
// ---------------------------------------------------------------------------
#define TAP4(A0, A1, A2, A3)                                 \
    {                                                        \
        f32x2 ad  = __builtin_elementwise_max(dxy, -dxy);    \
        f32x2 wv2 = __builtin_elementwise_max(one2 - ad, zero2); \
        float w = wv2.x * wv2.y;                             \
        f32x2 wv = {w, w};                                   \
        A0 = __builtin_elementwise_fma(wv, q0, A0);          \
        A1 = __builtin_elementwise_fma(wv, q1, A1);          \
        A2 = __builtin_elementwise_fma(wv, q2, A2);          \
        A3 = __builtin_elementwise_fma(wv, q3, A3);          \
        dxy += dd2;                                          \
    }

#define DETBODY(A0, A1, A2, A3, DX_, DY_, EX_, EY_)                        \
    {                                                                      \
        float Tx = DX_, Ty = DY_;                                          \
        float ts = fmaf(rx, Tx, ry * Ty);                                  \
        float sf = ceilf(fmaf(ts, INVDT, K0F));                            \
        sf = fminf(fmaxf(sf, 0.0f), (float)(NSAMP - 3));                   \
        float tt = fmaf(sf, DTF, T0F);                                     \
        f32x2 dxy = {fmaf(tt, Tx, -rx), fmaf(tt, Ty, -ry)};                \
        f32x2 dd2 = {EX_, EY_};                                            \
        f32x2 q0 = {r01.x, r01.y}, q1 = {r01.z, r01.w};                    \
        f32x2 q2 = {r23.x, r23.y}, q3 = {r23.z, r23.w};                    \
        TAP4(A0, A1, A2, A3)                                               \
        TAP4(A0, A1, A2, A3)                                               \
        TAP4(A0, A1, A2, A3)                                               \
    }

#define QTAPS(Q, A0, A1, A2, A3, DX_, DY_, EX_, EY_)                       \
    {                                                                      \
        float4 A = angG[90 * (Q) + am];                                    \
        float rx = fi - A.z, ry = fj - A.w;                                \
        float rpar  = -fmaf(rx, A.x, ry * A.y);                            \
        float rperp = fmaf(ry, A.x, -rx * A.y);                            \
        float us = 1000.0f * rperp * __builtin_amdgcn_rcpf(rpar);          \
        float dstar = fmaf(us, 0.625f, 223.5f);                            \
        float r2 = fmaf(rx, rx, ry * ry);                                  \
        float ir = rsqrtf(r2);                                             \
        float g  = fmaf(fabsf(rx) + fabsf(ry), ir, 0.031f);                \
        float kk = fmaf(us, us, 1.0e6f) * ir;                              \
        float dd = fmaf(g * kk, 6.25e-4f, 0.05f);                          \
        int dlo = (int)ceilf(dstar - dd);  if (dlo < 0) dlo = 0;           \
        int dhi = (int)floorf(dstar + dd); if (dhi > DET_N - 1) dhi = DET_N - 1; \
        int d = dlo;                                                       \
        for (; d < dhi; d += 2) {                                          \
            float4 DqA_  = sD[d];      float4 DqB_  = sD[d + 1];           \
            float4 r01A_ = sR0[d];     float4 r23A_ = sR1[d];              \
            float4 r01B_ = sR0[d + 1]; float4 r23B_ = sR1[d + 1];          \
            {                                                              \
                float4 Dq = DqA_; float4 r01 = r01A_, r23 = r23A_;         \
                DETBODY(A0, A1, A2, A3, DX_, DY_, EX_, EY_)                \
            }                                                              \
            {                                                              \
                float4 Dq = DqB_; float4 r01 = r01B_, r23 = r23B_;         \
                DETBODY(A0, A1, A2, A3, DX_, DY_, EX_, EY_)                \
            }                                                              \
        }                                                                  \
        if (d <= dhi) {                                                    \
            float4 Dq  = sD[d];                                            \
            float4 r01 = sR0[d], r23 = sR1[d];                             \
            DETBODY(A0, A1, A2, A3, DX_, DY_, EX_, EY_)                    \
        }                                                                  \
    }

template <int NSPLIT>
__global__ __launch_bounds__(256) void bp4_k(const float4* __restrict__ dirq,
                                             const float4* __restrict__ rvq,
                                             const float4* __restrict__ angG,
                                             float* __restrict__ bpp) {
    __shared__ float4 sD[DET_N];
    __shared__ float4 sR0[DET_N];
    __shared__ float4 sR1[DET_N];

    // grid is exact (NORB*NSPLIT % 256 == 0): no early return (barriers below)
    int tid = blockIdx.x * blockDim.x + threadIdx.x;
    int orb = tid % NORB;
    int sp  = tid / NORB;   // uniform across the WG (NORB % 256 == 0)
    // decode tile-swizzled orbit: wave = 8x8 pixel tile
    int tile  = orb >> 6;
    int intra = orb & 63;
    int ri = (tile % 20) * 8 + (intra & 7);
    int rj = (tile / 20) * 8 + (intra >> 3);
    float fi = (float)ri, fj = (float)rj;

    const f32x2 one2 = {1.0f, 1.0f}, zero2 = {0.0f, 0.0f};
    f32x2 acc0 = {0.0f, 0.0f}, acc1 = acc0, acc2 = acc0, acc3 = acc0;

    bool first = true;
    for (int am = sp; am < 90; am += NSPLIT) {
        const float4* Drow = dirq + am * DET_N;
        const float4* Rrow = rvq + am * DET_N * 2;
        if (!first) __syncthreads();   // previous compute done
        first = false;
        for (int i = threadIdx.x; i < DET_N; i += 256) {
            sD[i]  = Drow[i];
            sR0[i] = Rrow[2 * i];
            sR1[i] = Rrow[2 * i + 1];
        }
        __syncthreads();   // rows staged

        QTAPS(0, acc0, acc1, acc2, acc3,  Dq.x,  Dq.y,  Dq.z,  Dq.w)
        QTAPS(1, acc3, acc0, acc1, acc2, -Dq.y,  Dq.x, -Dq.w,  Dq.z)
        QTAPS(2, acc2, acc3, acc0, acc1, -Dq.x, -Dq.y, -Dq.z, -Dq.w)
        QTAPS(3, acc1, acc2, acc3, acc0,  Dq.y, -Dq.x,  Dq.w, -Dq.z)
    }

    int base = sp * 8 * NORB + orb;
    bpp[base           ] = acc0.x;
    bpp[base + 1 * NORB] = acc0.y;
    bpp[base + 2 * NORB] = acc1.x;
    bpp[base + 3 * NORB] = acc1.y;
    bpp[base + 4 * NORB] = acc2.x;
    bpp[base + 5 * NORB] = acc2.y;
    bpp[base + 6 * NORB] = acc3.x;
    bpp[base + 7 * NORB] = acc3.y;
}

template <int NSPLIT>
__global__ __launch_bounds__(256) void combine4_k(const float* __restrict__ x,
                                                  const float* __restrict__ bpp,
                                                  float* __restrict__ out) {
    int tid = blockIdx.x * blockDim.x + threadIdx.x;
    if (tid >= NB * NPIX) return;
    int i = tid % NN;
    int j = (tid / NN) % NN;
    int b = tid / NPIX;
    int k, ri, rj;
    if (j < 160) {
        if (i < 160) { k = 0; ri = i;       rj = j;       }
        else         { k = 1; ri = j;       rj = 319 - i; }
    } else {
        if (i >= 160){ k = 2; ri = 319 - i; rj = 319 - j; }
        else         { k = 3; ri = 319 - j; rj = i;       }
    }
    int off = (k * 2 + b) * NORB + orb_swizzle(ri, rj);
    float s = x[tid];
#pragma unroll
    for (int sp = 0; sp < NSPLIT; ++sp) s += bpp[sp * 8 * NORB + off];
    out[tid] = s;
}

// ---------------------------------------------------------------------------
// Fallback kernels (round-7 proven, fully exact)
// ---------------------------------------------------------------------------
template <bool USE_TAB>
__global__ __launch_bounds__(256) void residual_k(const float* __restrict__ x,
                                                  const float* __restrict__ p,
                                                  void* __restrict__ tabv) {
    int tid = blockIdx.x * blockDim.x + threadIdx.x;
    if (tid >= NRAY) return;
    int d = tid % DET_N, a = tid / DET_N;
    double beta = (double)a * (M_PI / 180.0);
    double cbd = cos(beta), sbd = sin(beta);
    double u = ((double)d - 223.5) * 1.6;
    double inorm = 1.0 / sqrt(1.0e6 + u * u);
    float dirx = (float)((-1000.0 * cbd - u * sbd) * inorm);
    float diry = (float)((-1000.0 * sbd + u * cbd) * inorm);
    float sx = (float)(500.0 * cbd + 159.5);
    float sy = (float)(500.0 * sbd + 159.5);
    const float* __restrict__ v0 = x;
    const float* __restrict__ v1 = x + NPIX;
    float acc0 = 0.0f, acc1 = 0.0f;
    for (int s = 0; s < NSAMP; ++s) {
        float t  = fmaf((float)s, DTF, T0F);
        float ix = fmaf(t, dirx, sx);
        float iy = fmaf(t, diry, sy);
        float xf = floorf(ix), yf = floorf(iy);
        int x0 = (int)xf, y0 = (int)yf;
        if (x0 < -1 || x0 >= NN || y0 < -1 || y0 >= NN) continue;
        float fx = ix - xf, fy = iy - yf;
        int x1 = x0 + 1, y1 = y0 + 1;
        bool vx0 = (x0 >= 0), vx1 = (x1 < NN);
        bool vy0 = (y0 >= 0), vy1 = (y1 < NN);
        int x0c = vx0 ? x0 : 0, x1c = vx1 ? x1 : NN - 1;
        int y0c = vy0 ? y0 : 0, y1c = vy1 ? y1 : NN - 1;
        int i00 = y0c * NN + x0c, i01 = y0c * NN + x1c;
        int i10 = y1c * NN + x0c, i11 = y1c * NN + x1c;
        float gx = 1.0f - fx, gy = 1.0f - fy;
        float w00 = (vx0 && vy0) ? gx * gy : 0.0f;
        float w01 = (vx1 && vy0) ? fx * gy : 0.0f;
        float w10 = (vx0 && vy1) ? gx * fy : 0.0f;
        float w11 = (vx1 && vy1) ? fx * fy : 0.0f;
        acc0 = fmaf(v0[i00], w00, acc0); acc0 = fmaf(v0[i01], w01, acc0);
        acc0 = fmaf(v0[i10], w10, acc0); acc0 = fmaf(v0[i11], w11, acc0);
        acc1 = fmaf(v1[i00], w00, acc1); acc1 = fmaf(v1[i01], w01, acc1);
        acc1 = fmaf(v1[i10], w10, acc1); acc1 = fmaf(v1[i11], w11, acc1);
    }
    float rv0 = -fmaf(acc0, DTF, -p[tid]) * DTF;
    float rv1 = -fmaf(acc1, DTF, -p[NRAY + tid]) * DTF;
    if constexpr (USE_TAB) {
        ((float4*)tabv)[tid] = make_float4(dirx, diry, rv0, rv1);
    } else {
        ((float2*)tabv)[tid] = make_float2(rv0, rv1);
    }
}

template <int NSPLIT, bool DIRECT, bool USE_TAB>
__global__ __launch_bounds__(256) void bp_k(const void* __restrict__ tabv,
                                            const float* __restrict__ x,
                                            float* __restrict__ outp) {
    __shared__ float4 ang[A_NUM];
    for (int a = threadIdx.x; a < A_NUM; a += blockDim.x) {
        double beta = (double)a * (M_PI / 180.0);
        double cbd = cos(beta), sbd = sin(beta);
        ang[a] = make_float4((float)cbd, (float)sbd,
                             (float)(500.0 * cbd + 159.5),
                             (float)(500.0 * sbd + 159.5));
    }
    __syncthreads();

    int tid = blockIdx.x * blockDim.x + threadIdx.x;
    if (tid >= NPIX * NSPLIT) return;
    int pix = tid % NPIX;
    int sp  = tid / NPIX;
    float fi = (float)(pix % NN), fj = (float)(pix / NN);

    float acc0 = 0.0f, acc1 = 0.0f;

    for (int a = sp; a < A_NUM; a += NSPLIT) {
        float4 A = ang[a];
        float rx = fi - A.z, ry = fj - A.w;
        float rpar  = -fmaf(rx, A.x, ry * A.y);
        float rperp = fmaf(ry, A.x, -rx * A.y);
        float us = 1000.0f * rperp * __builtin_amdgcn_rcpf(rpar);
        float dstar = fmaf(us, 0.625f, 223.5f);
        float r2 = fmaf(rx, rx, ry * ry);
        float kk = fmaf(us, us, 1.0e6f) * rsqrtf(r2);
        float dd = fmaf(kk, 8.8394e-4f, 0.05f);
        int dlo = (int)ceilf(dstar - dd);  if (dlo < 0) dlo = 0;
        int dhi = (int)floorf(dstar + dd); if (dhi > DET_N - 1) dhi = DET_N - 1;

        const float4* __restrict__ Trow =
            USE_TAB ? ((const float4*)tabv) + a * DET_N : nullptr;
        const float2* __restrict__ RVrow =
            USE_TAB ? nullptr : ((const float2*)tabv) + a * DET_N;

        for (int d = dlo; d <= dhi; ++d) {
            float dirx, diry, rv0, rv1;
            if constexpr (USE_TAB) {
                float4 T = Trow[d];
                dirx = T.x; diry = T.y; rv0 = T.z; rv1 = T.w;
            } else {
                float u = ((float)d - 223.5f) * 1.6f;
                float inv = rsqrtf(fmaf(u, u, 1.0e6f));
                dirx = fmaf(-1000.0f, A.x, -u * A.y) * inv;
                diry = fmaf(-1000.0f, A.y,  u * A.x) * inv;
                float2 RV = RVrow[d];
                rv0 = RV.x; rv1 = RV.y;
            }
            float ts = fmaf(rx, dirx, ry * diry);
            float sf = ceilf(fmaf(ts, INVDT, K0F));
            sf = fminf(fmaxf(sf, 0.0f), (float)(NSAMP - 3));
            float tt = fmaf(sf, DTF, T0F);
            float dx = fmaf(tt, dirx, -rx);
            float dy = fmaf(tt, diry, -ry);
            float ddx = DTF * dirx, ddy = DTF * diry;
#pragma unroll
            for (int k = 0; k < 3; ++k) {
                float wx = fmaxf(1.0f - fabsf(dx), 0.0f);
                float wy = fmaxf(1.0f - fabsf(dy), 0.0f);
                float w = wx * wy;
                acc0 = fmaf(w, rv0, acc0);
                acc1 = fmaf(w, rv1, acc1);
                dx += ddx; dy += ddy;
            }
        }
    }

    if constexpr (DIRECT) {
        outp[pix]        = x[pix]        + acc0;
        outp[NPIX + pix] = x[NPIX + pix] + acc1;
    } else {
        outp[(sp * 2 + 0) * NPIX + pix] = acc0;
        outp[(sp * 2 + 1) * NPIX + pix] = acc1;
    }
}

template <int NSPLIT>
__global__ __launch_bounds__(256) void combine_k(const float* __restrict__ x,
                                                 const float* __restrict__ part,
                                                 float* __restrict__ out) {
    int tid = blockIdx.x * blockDim.x + threadIdx.x;
    if (tid >= NB * NPIX) return;
    int pix = tid % NPIX, b = tid / NPIX;
    float s = x[tid];
#pragma unroll
    for (int sp = 0; sp < NSPLIT; ++sp) s += part[(sp * 2 + b) * NPIX + pix];
    out[tid] = s;
}

extern "C" void kernel_launch(void* const* d_in, const int* in_sizes, int n_in,
                              void* d_out, int out_size, void* d_ws, size_t ws_size,
                              hipStream_t stream) {
    const float* x = (const float*)d_in[0];   // [2,320,320]
    const float* p = (const float*)d_in[1];   // [2,360,448]
    float* out = (float*)d_out;               // [2,320,320]
    char* ws = (char*)d_ws;

    // Layout (bytes):
    //  dirq @ 0          (  645,120)  prep..bp4 (float4)
    //  tabD @ 645,120    (1,290,240)  prep..partial   } same region
    //  rvq  @ 645,120    (1,290,240)  finalize4..bp4  } (sequential lifetimes)
    //  tabS @ 1,935,360  (    8,192)
    //  angG @ 1,943,552  (    8,192)  prep..bp4
    //  xqb  @ 1,951,744  (1,679,616)  interleave..partial  (PN^2 uint4 fp16)
    //  xqbT @ 3,631,360  (1,679,616)  interleave..partial
    //  fpart@ 5,310,976  (5,160,960)  partial..finalize4   -> end 10,471,936
    //  bpp  @ 1,951,744  (NSPLIT*8*NORB*4) bp4..combine4 (over dead xqb/xqbT/fpart)
    const size_t bpp15_bytes = (size_t)NSPQ15 * 8 * NORB * 4; // 12.29 MB
    const size_t bpp12_bytes = (size_t)NSPQ12 * 8 * NORB * 4; // 9.83 MB
    const size_t NEED15 = 1951744 + bpp15_bytes;              // 14,239,744 (r4 proven)
    const size_t NEED12 = 1951744 + bpp12_bytes;              // 11,782,144
    const size_t NEED8  = 10471936;

    const size_t tab_bytes  = sizeof(float4) * NRAY;           // 2.58 MB
    const size_t bpp4_bytes = sizeof(float) * 8 * NPIX;        // 3.28 MB

    if (ws_size >= NEED12 || ws_size >= NEED8) {
        float4* dirq  = (float4*)(ws + 0);
        float2* tabD  = (float2*)(ws + 645120);
        float4* rvq   = (float4*)(ws + 645120);
        float4* tabS  = (float4*)(ws + 1935360);
        float4* angG  = (float4*)(ws + 1943552);
        uint4*  xqb   = (uint4*)(ws + 1951744);
        uint4*  xqbT  = (uint4*)(ws + 3631360);
        float2* fpart = (float2*)(ws + 5310976);
        float*  bpp   = (float*)(ws + 1951744);

        prep_k<<<NRAY / 256, 256, 0, stream>>>(tabD, tabS, dirq, angG);
        interleaveQB_k<<<(PN * PN + 255) / 256, 256, 0, stream>>>(x, xqb);
        interleaveQBT_k<<<(PN * PN + 255) / 256, 256, 0, stream>>>(x, xqbT);
        partial_k<<<(NRAY * NCH) / 256, 256, 0, stream>>>(tabD, tabS, xqb, xqbT, fpart);
        finalize4_k<<<(90 * DET_N + 255) / 256, 256, 0, stream>>>(p, fpart, rvq);
        if (ws_size >= NEED15) {
            bp4_k<NSPQ15><<<(NORB * NSPQ15) / 256, 256, 0, stream>>>(dirq, rvq, angG, bpp);
            combine4_k<NSPQ15><<<(NB * NPIX) / 256, 256, 0, stream>>>(x, bpp, out);
        } else if (ws_size >= NEED12) {
            bp4_k<NSPQ12><<<(NORB * NSPQ12) / 256, 256, 0, stream>>>(dirq, rvq, angG, bpp);
            combine4_k<NSPQ12><<<(NB * NPIX) / 256, 256, 0, stream>>>(x, bpp, out);
        } else {
            bp4_k<8><<<(NORB * 8) / 256, 256, 0, stream>>>(dirq, rvq, angG, bpp);
            combine4_k<8><<<(NB * NPIX) / 256, 256, 0, stream>>>(x, bpp, out);
        }
    } else if (ws_size >= tab_bytes + bpp4_bytes) {
        float4* tab = (float4*)ws;
        float* bpp  = (float*)(ws + tab_bytes);
        residual_k<true><<<(NRAY + 255) / 256, 256, 0, stream>>>(x, p, tab);
        bp_k<4, false, true><<<(NPIX * 4) / 256, 256, 0, stream>>>(tab, x, bpp);
        combine_k<4><<<(NB * NPIX + 255) / 256, 256, 0, stream>>>(x, bpp, out);
    } else if (ws_size >= tab_bytes) {
        float4* tab = (float4*)ws;
        residual_k<true><<<(NRAY + 255) / 256, 256, 0, stream>>>(x, p, tab);
        bp_k<1, true, true><<<NPIX / 256, 256, 0, stream>>>(tab, x, out);
    } else {
        float2* rw2 = (float2*)ws;
        residual_k<false><<<(NRAY + 255) / 256, 256, 0, stream>>>(x, p, rw2);
        bp_k<1, true, false><<<NPIX / 256, 256, 0, stream>>>(rw2, x, out);
    }
}

// Round 12
// 141.228 us; speedup vs baseline: 1.0246x; 1.0246x over previous
//
#include <hip/hip_runtime.h>
#include <hip/hip_fp16.h>
#include <math.h>

#define A_NUM 360
#define DET_N 448
#define NN 320
#define NSAMP 452
#define NB 2
#define NPIX (NN * NN)
#define NRAY (A_NUM * DET_N)
#define NCH 4
#define CHS (NSAMP / NCH)   // 113
#define NORB 25600          // 160*160 rotation orbits
#define NSPQ15 15           // bp4 angle splits (90/15=6 even; ws-proven tier)
#define NSPQ12 12           // mid tier
#define PN 324              // padded dim (+2 each side)

// R = 320*sqrt(2)/2, DT = 2R/452, t0 = 500 - R + 0.5*DT
#define R_D   226.27416997969522
#define DT_D  (2.0 * R_D / (double)NSAMP)
#define T0_D  (500.0 - R_D + 0.5 * DT_D)
#define DTF   ((float)DT_D)
#define T0F   ((float)T0_D)
#define INVDT ((float)(1.0 / DT_D))
#define K0F   ((float)((-1.4150 - T0_D) * (1.0 / DT_D)))

typedef float f32x2 __attribute__((ext_vector_type(2)));

// tile swizzle: orbit index <-> (ri,rj) with 8x8 tiles (20x20 tile grid).
// wave (64 lanes) = one 8x8 pixel tile (round-5 proven, 92->77us).
__device__ __forceinline__ int orb_swizzle(int ri, int rj) {
    int tile = (rj >> 3) * 20 + (ri >> 3);
    int intra = ((rj & 7) << 3) | (ri & 7);
    return (tile << 6) | intra;
}

// ---------------------------------------------------------------------------
// prep: tabD[ray]=(dirx,diry); tabS[a]=(cb,sb, padded srcx, padded srcy);
//       dirq[am<90][d]=(dirx,diry,DT*dirx,DT*diry);
//       angG[a]=(cb,sb, srcx+159.5, srcy+159.5)
// ---------------------------------------------------------------------------
__global__ __launch_bounds__(256) void prep_k(float2* __restrict__ tabD,
                                              float4* __restrict__ tabS,
                                              float4* __restrict__ dirq,
                                              float4* __restrict__ angG) {
    int tid = blockIdx.x * blockDim.x + threadIdx.x;
    if (tid >= NRAY) return;
    int d = tid % DET_N, a = tid / DET_N;
    double beta = (double)a * (M_PI / 180.0);
    double cbd = cos(beta), sbd = sin(beta);
    double u = ((double)d - 223.5) * 1.6;
    double inorm = 1.0 / sqrt(1.0e6 + u * u);
    float dx = (float)((-1000.0 * cbd - u * sbd) * inorm);
    float dy = (float)((-1000.0 * sbd + u * cbd) * inorm);
    tabD[tid] = make_float2(dx, dy);
    if (d == 0) {
        tabS[a] = make_float4((float)cbd, (float)sbd,
                              (float)(500.0 * cbd + 161.5),   // +2 pad
                              (float)(500.0 * sbd + 161.5));  // +2 pad
        angG[a] = make_float4((float)cbd, (float)sbd,
                              (float)(500.0 * cbd + 159.5),
                              (float)(500.0 * sbd + 159.5));
    }
    if (a < 90) dirq[a * DET_N + d] = make_float4(dx, dy, DTF * dx, DTF * dy);
}

// pack (batch0, batch1) at pixel idx as fp16 pair (b0 low, b1 high); 0 if invalid
__device__ __forceinline__ unsigned packpix(const float* __restrict__ x,
                                            bool v, int idx) {
    if (!v) return 0u;
    __half2 h = __floats2half2_rn(x[idx], x[NPIX + idx]);
    return *reinterpret_cast<unsigned*>(&h);
}
__device__ __forceinline__ f32x2 up16(unsigned w) {
    __half2 h = *reinterpret_cast<__half2*>(&w);
    return (f32x2){__low2float(h), __high2float(h)};
}

// fp16-quad row-major: cell t=(py*PN+px), words = pixels (x0,y0),(x0+1,y0),
// (x0,y0+1),(x0+1,y0+1) in orig coords (pad shift -2).
__global__ __launch_bounds__(256) void interleaveQB_k(const float* __restrict__ x,
                                                      uint4* __restrict__ xb) {
    int t = blockIdx.x * blockDim.x + threadIdx.x;
    if (t >= PN * PN) return;
    int px = t % PN, py = t / PN;
    int ox = px - 2, oy = py - 2;
    bool cx0 = (ox >= 0) && (ox < NN);
    bool cx1 = (ox + 1 >= 0) && (ox + 1 < NN);
    bool cy0 = (oy >= 0) && (oy < NN);
    bool cy1 = (oy + 1 >= 0) && (oy + 1 < NN);
    int b = oy * NN + ox;
    uint4 w;
    w.x = packpix(x, cx0 && cy0, b);
    w.y = packpix(x, cx1 && cy0, b + 1);
    w.z = packpix(x, cx0 && cy1, b + NN);
    w.w = packpix(x, cx1 && cy1, b + NN + 1);
    xb[t] = w;
}

// fp16-quad transposed: t: r=t%PN (ps-x = orig row), q=t/PN (ps-y = orig col)
__global__ __launch_bounds__(256) void interleaveQBT_k(const float* __restrict__ x,
                                                       uint4* __restrict__ xbT) {
    int t = blockIdx.x * blockDim.x + threadIdx.x;
    if (t >= PN * PN) return;
    int r = t % PN, q = t / PN;
    int row0 = r - 2, col0 = q - 2;
    bool r0v = (row0 >= 0) && (row0 < NN);
    bool r1v = (row0 + 1 >= 0) && (row0 + 1 < NN);
    bool c0v = (col0 >= 0) && (col0 < NN);
    bool c1v = (col0 + 1 >= 0) && (col0 + 1 < NN);
    int b = row0 * NN + col0;
    uint4 w;
    w.x = packpix(x, r0v && c0v, b);
    w.y = packpix(x, r1v && c0v, b + NN);
    w.z = packpix(x, r0v && c1v, b + 1);
    w.w = packpix(x, r1v && c1v, b + NN + 1);
    xbT[t] = w;
}

// ---------------------------------------------------------------------------
// partial forward projection (round-10 proven: slab skip + wave-tile swizzle
// + explicit 2-deep software pipeline).
// ---------------------------------------------------------------------------
__device__ __forceinline__ void samp1(const uint4* __restrict__ buf,
                                      float ix, float iy,
                                      f32x2& accA, f32x2& accB) {
    float xf = floorf(ix), yf = floorf(iy);
    float fx = ix - xf, fy = iy - yf;
    int idx = (int)yf * PN + (int)xf;
    uint4 qv = buf[idx];
    float gx = 1.0f - fx, gy = 1.0f - fy;
    float w00 = gx * gy, w01 = fx * gy, w10 = gx * fy, w11 = fx * fy;
    accA = __builtin_elementwise_fma((f32x2){w00, w00}, up16(qv.x), accA);
    accB = __builtin_elementwise_fma((f32x2){w01, w01}, up16(qv.y), accB);
    accA = __builtin_elementwise_fma((f32x2){w10, w10}, up16(qv.z), accA);
    accB = __builtin_elementwise_fma((f32x2){w11, w11}, up16(qv.w), accB);
}

#define PLOAD(Q0, Q1, Q2, Q3, FX, FY)                                  \
    {                                                                  \
        float x0_ = lx,               y0_ = ly;                        \
        float x1_ = lx + stx,         y1_ = ly + sty;                  \
        float x2_ = lx + 2.0f * stx,  y2_ = ly + 2.0f * sty;           \
        float x3_ = lx + 3.0f * stx,  y3_ = ly + 3.0f * sty;           \
        float xf0_ = floorf(x0_), yf0_ = floorf(y0_);                  \
        float xf1_ = floorf(x1_), yf1_ = floorf(y1_);                  \
        float xf2_ = floorf(x2_), yf2_ = floorf(y2_);                  \
        float xf3_ = floorf(x3_), yf3_ = floorf(y3_);                  \
        Q0 = buf[(int)yf0_ * PN + (int)xf0_];                          \
        Q1 = buf[(int)yf1_ * PN + (int)xf1_];                          \
        Q2 = buf[(int)yf2_ * PN + (int)xf2_];                          \
        Q3 = buf[(int)yf3_ * PN + (int)xf3_];                          \
        FX##0 = x0_ - xf0_; FY##0 = y0_ - yf0_;                        \
        FX##1 = x1_ - xf1_; FY##1 = y1_ - yf1_;                        \
        FX##2 = x2_ - xf2_; FY##2 = y2_ - yf2_;                        \
        FX##3 = x3_ - xf3_; FY##3 = y3_ - yf3_;                        \
        lx += 4.0f * stx; ly += 4.0f * sty;                            \
    }

#define PCONS(Q0, Q1, Q2, Q3, FX, FY)                                  \
    {                                                                  \
        float gx0_ = 1.0f - FX##0, gy0_ = 1.0f - FY##0;                \
        float gx1_ = 1.0f - FX##1, gy1_ = 1.0f - FY##1;                \
        float gx2_ = 1.0f - FX##2, gy2_ = 1.0f - FY##2;                \
        float gx3_ = 1.0f - FX##3, gy3_ = 1.0f - FY##3;                \
        float w_;                                                      \
        w_ = gx0_ * gy0_;  accA = __builtin_elementwise_fma((f32x2){w_, w_}, up16(Q0.x), accA); \
        w_ = FX##0 * gy0_; accB = __builtin_elementwise_fma((f32x2){w_, w_}, up16(Q0.y), accB); \
        w_ = gx0_ * FY##0; accA = __builtin_elementwise_fma((f32x2){w_, w_}, up16(Q0.z), accA); \
        w_ = FX##0 * FY##0;accB = __builtin_elementwise_fma((f32x2){w_, w_}, up16(Q0.w), accB); \
        w_ = gx1_ * gy1_;  accA = __builtin_elementwise_fma((f32x2){w_, w_}, up16(Q1.x), accA); \
        w_ = FX##1 * gy1_; accB = __builtin_elementwise_fma((f32x2){w_, w_}, up16(Q1.y), accB); \
        w_ = gx1_ * FY##1; accA = __builtin_elementwise_fma((f32x2){w_, w_}, up16(Q1.z), accA); \
        w_ = FX##1 * FY##1;accB = __builtin_elementwise_fma((f32x2){w_, w_}, up16(Q1.w), accB); \
        w_ = gx2_ * gy2_;  accA = __builtin_elementwise_fma((f32x2){w_, w_}, up16(Q2.x), accA); \
        w_ = FX##2 * gy2_; accB = __builtin_elementwise_fma((f32x2){w_, w_}, up16(Q2.y), accB); \
        w_ = gx2_ * FY##2; accA = __builtin_elementwise_fma((f32x2){w_, w_}, up16(Q2.z), accA); \
        w_ = FX##2 * FY##2;accB = __builtin_elementwise_fma((f32x2){w_, w_}, up16(Q2.w), accB); \
        w_ = gx3_ * gy3_;  accA = __builtin_elementwise_fma((f32x2){w_, w_}, up16(Q3.x), accA); \
        w_ = FX##3 * gy3_; accB = __builtin_elementwise_fma((f32x2){w_, w_}, up16(Q3.y), accB); \
        w_ = gx3_ * FY##3; accA = __builtin_elementwise_fma((f32x2){w_, w_}, up16(Q3.z), accA); \
        w_ = FX##3 * FY##3;accB = __builtin_elementwise_fma((f32x2){w_, w_}, up16(Q3.w), accB); \
    }

__global__ __launch_bounds__(256) void partial_k(const float2* __restrict__ tabD,
                                                 const float4* __restrict__ tabS,
                                                 const uint4* __restrict__ bufR,
                                                 const uint4* __restrict__ bufT,
                                                 float2* __restrict__ part) {
    int tid = blockIdx.x * blockDim.x + threadIdx.x;
    if (tid >= NRAY * NCH) return;
    // wave-tile swizzle: lane = d_lo(4b) | c(2b); upper bits = (a, d_hi)
    int d_lo = tid & 15;
    int c    = (tid >> 4) & 3;
    int rest = tid >> 6;            // [0, 360*28)
    int d_hi = rest % (DET_N / 16); // 28 det-groups
    int a    = rest / (DET_N / 16);
    int ray  = a * DET_N + d_hi * 16 + d_lo;

    float2 D = tabD[ray];
    float4 S = tabS[a];
    bool swp = fabsf(S.x) > fabsf(S.y);
    float dirx = swp ? D.y : D.x;
    float diry = swp ? D.x : D.y;
    float sx   = swp ? S.w : S.z;
    float sy   = swp ? S.z : S.w;
    const uint4* __restrict__ buf = swp ? bufT : bufR;

    // slab intersection: t-range where ix,iy both in [0.5, 322.5]
    float invx = __builtin_amdgcn_rcpf(dirx);
    float invy = __builtin_amdgcn_rcpf(diry);
    float tx1 = (0.5f   - sx) * invx;
    float tx2 = (322.5f - sx) * invx;
    float ty1 = (0.5f   - sy) * invy;
    float ty2 = (322.5f - sy) * invy;
    float tmn = fmaxf(fminf(tx1, tx2), fminf(ty1, ty2));
    float tmx = fminf(fmaxf(tx1, tx2), fmaxf(ty1, ty2));
    float smnf = fminf(fmaxf(ceilf((tmn - T0F) * INVDT), 0.0f), (float)(NSAMP - 1));
    float smxf = fminf(fmaxf(floorf((tmx - T0F) * INVDT), 0.0f), (float)(NSAMP - 1));
    int smin = (int)smnf;
    int smax = (int)smxf;
    // this chunk covers samples s = c + 4k, k in [0, CHS)
    int klo = (smin - c + 3) >> 2;  if (klo < 0) klo = 0;
    int khi = (smax - c) >> 2;      if (khi > CHS - 1) khi = CHS - 1;
    int kn = khi - klo + 1;
    if (kn < 0) kn = 0;

    float t0c = fmaf((float)(c + 4 * klo), DTF, T0F);
    float lx = fmaf(t0c, dirx, sx);
    float ly = fmaf(t0c, diry, sy);
    float stx = (4.0f * DTF) * dirx;
    float sty = (4.0f * DTF) * diry;

    f32x2 accA = {0.0f, 0.0f}, accB = {0.0f, 0.0f};

    int nblk = kn >> 2;
    int rem  = kn & 3;

    uint4 qa0, qa1, qa2, qa3, qb0, qb1, qb2, qb3;
    float fxa0, fxa1, fxa2, fxa3, fya0, fya1, fya2, fya3;
    float fxb0, fxb1, fxb2, fxb3, fyb0, fyb1, fyb2, fyb3;

    if (nblk > 0) {
        PLOAD(qa0, qa1, qa2, qa3, fxa, fya)
        int b = 1;
        for (; b + 1 < nblk; b += 2) {
            PLOAD(qb0, qb1, qb2, qb3, fxb, fyb)
            PCONS(qa0, qa1, qa2, qa3, fxa, fya)
            PLOAD(qa0, qa1, qa2, qa3, fxa, fya)
            PCONS(qb0, qb1, qb2, qb3, fxb, fyb)
        }
        if (b < nblk) {
            PLOAD(qb0, qb1, qb2, qb3, fxb, fyb)
            PCONS(qa0, qa1, qa2, qa3, fxa, fya)
            PCONS(qb0, qb1, qb2, qb3, fxb, fyb)
        } else {
            PCONS(qa0, qa1, qa2, qa3, fxa, fya)
        }
    }
    for (int r = 0; r < rem; ++r) {
        samp1(buf, lx, ly, accA, accB);
        lx += stx; ly += sty;
    }

    f32x2 acc = accA + accB;
    part[c * NRAY + ray] = make_float2(acc.x, acc.y);
}

// ---------------------------------------------------------------------------
// finalize4: reduce chunk partials (fixed order), pack rv rotation-quads
// ---------------------------------------------------------------------------
__global__ __launch_bounds__(256) void finalize4_k(const float* __restrict__ p,
                                                   const float2* __restrict__ part,
                                                   float4* __restrict__ rvq) {
    int tid = blockIdx.x * blockDim.x + threadIdx.x;
    if (tid >= 90 * DET_N) return;
    int d = tid % DET_N, am = tid / DET_N;
    float rv[8];
#pragma unroll
    for (int k = 0; k < 4; ++k) {
        int ray = (am + 90 * k) * DET_N + d;
        float a0 = 0.0f, a1 = 0.0f;
#pragma unroll
        for (int c = 0; c < NCH; ++c) {
            float2 pr = part[c * NRAY + ray];
            a0 += pr.x; a1 += pr.y;
        }
        rv[2 * k]     = -fmaf(a0, DTF, -p[ray]) * DTF;
        rv[2 * k + 1] = -fmaf(a1, DTF, -p[NRAY + ray]) * DTF;
    }
    rvq[2 * tid]     = make_float4(rv[0], rv[1], rv[2], rv[3]);
    rvq[2 * tid + 1] = make_float4(rv[4], rv[5], rv[6], rv[7]);
}

// ---------------------------------------------------------------------------
// bp4: 4-fold rotation symmetric adjoint — round-9 proven form (best bp4:
// LDS row staging, float4 sD, no sAng table, simple ascending-d loop).
// bp4 declared at its ~70us structural floor after 5 falsified alternatives
// (occupancy x2, LDS traffic cut, 2 unroll shapes — all neutral/regressed).
// ---------------------------------------------------------------------------
#define TAP4(A0, A1, A2, A3)                                 \
    {                                                        \
        f32x2 ad  = __builtin_elementwise_max(dxy, -dxy);    \
        f32x2 wv2 = __builtin_elementwise_max(one2 - ad, zero2); \
        float w = wv2.x * wv2.y;                             \
        f32x2 wv = {w, w};                                   \
        A0 = __builtin_elementwise_fma(wv, q0, A0);          \
        A1 = __builtin_elementwise_fma(wv, q1, A1);          \
        A2 = __builtin_elementwise_fma(wv, q2, A2);          \
        A3 = __builtin_elementwise_fma(wv, q3, A3);          \
        dxy += dd2;                                          \
    }

#define QTAPS(Q, A0, A1, A2, A3, DX_, DY_, EX_, EY_)                       \
    {                                                                      \
        float4 A = angG[90 * (Q) + am];                                    \
        float rx = fi - A.z, ry = fj - A.w;                                \
        float rpar  = -fmaf(rx, A.x, ry * A.y);                            \
        float rperp = fmaf(ry, A.x, -rx * A.y);                            \
        float us = 1000.0f * rperp * __builtin_amdgcn_rcpf(rpar);          \
        float dstar = fmaf(us, 0.625f, 223.5f);                            \
        float r2 = fmaf(rx, rx, ry * ry);                                  \
        float ir = rsqrtf(r2);                                             \
        float g  = fmaf(fabsf(rx) + fabsf(ry), ir, 0.031f);                \
        float kk = fmaf(us, us, 1.0e6f) * ir;                              \
        float dd = fmaf(g * kk, 6.25e-4f, 0.05f);                          \
        int dlo = (int)ceilf(dstar - dd);  if (dlo < 0) dlo = 0;           \
        int dhi = (int)floorf(dstar + dd); if (dhi > DET_N - 1) dhi = DET_N - 1; \
        for (int d = dlo; d <= dhi; ++d) {                                 \
            float4 Dq  = sD[d];                                            \
            float4 r01 = sR0[d];                                           \
            float4 r23 = sR1[d];                                           \
            float Tx = DX_, Ty = DY_;                                      \
            float ts = fmaf(rx, Tx, ry * Ty);                              \
            float sf = ceilf(fmaf(ts, INVDT, K0F));                        \
            sf = fminf(fmaxf(sf, 0.0f), (float)(NSAMP - 3));               \
            float tt = fmaf(sf, DTF, T0F);                                 \
            f32x2 dxy = {fmaf(tt, Tx, -rx), fmaf(tt, Ty, -ry)};            \
            f32x2 dd2 = {EX_, EY_};                                        \
            f32x2 q0 = {r01.x, r01.y}, q1 = {r01.z, r01.w};                \
            f32x2 q2 = {r23.x, r23.y}, q3 = {r23.z, r23.w};                \
            TAP4(A0, A1, A2, A3)                                           \
            TAP4(A0, A1, A2, A3)                                           \
            TAP4(A0, A1, A2, A3)                                           \
        }                                                                  \
    }

template <int NSPLIT>
__global__ __launch_bounds__(256) void bp4_k(const float4* __restrict__ dirq,
                                             const float4* __restrict__ rvq,
                                             const float4* __restrict__ angG,
                                             float* __restrict__ bpp) {
    __shared__ float4 sD[DET_N];
    __shared__ float4 sR0[DET_N];
    __shared__ float4 sR1[DET_N];

    // grid is exact (NORB*NSPLIT % 256 == 0): no early return (barriers below)
    int tid = blockIdx.x * blockDim.x + threadIdx.x;
    int orb = tid % NORB;
    int sp  = tid / NORB;   // uniform across the WG (NORB % 256 == 0)
    // decode tile-swizzled orbit: wave = 8x8 pixel tile
    int tile  = orb >> 6;
    int intra = orb & 63;
    int ri = (tile % 20) * 8 + (intra & 7);
    int rj = (tile / 20) * 8 + (intra >> 3);
    float fi = (float)ri, fj = (float)rj;

    const f32x2 one2 = {1.0f, 1.0f}, zero2 = {0.0f, 0.0f};
    f32x2 acc0 = {0.0f, 0.0f}, acc1 = acc0, acc2 = acc0, acc3 = acc0;

    bool first = true;
    for (int am = sp; am < 90; am += NSPLIT) {
        const float4* Drow = dirq + am * DET_N;
        const float4* Rrow = rvq + am * DET_N * 2;
        if (!first) __syncthreads();   // previous compute done
        first = false;
        for (int i = threadIdx.x; i < DET_N; i += 256) {
            sD[i]  = Drow[i];
            sR0[i] = Rrow[2 * i];
            sR1[i] = Rrow[2 * i + 1];
        }
        __syncthreads();   // rows staged

        QTAPS(0, acc0, acc1, acc2, acc3,  Dq.x,  Dq.y,  Dq.z,  Dq.w)
        QTAPS(1, acc3, acc0, acc1, acc2, -Dq.y,  Dq.x, -Dq.w,  Dq.z)
        QTAPS(2, acc2, acc3, acc0, acc1, -Dq.x, -Dq.y, -Dq.z, -Dq.w)
        QTAPS(3, acc1, acc2, acc3, acc0,  Dq.y, -Dq.x,  Dq.w, -Dq.z)
    }

    int base = sp * 8 * NORB + orb;
    bpp[base           ] = acc0.x;
    bpp[base + 1 * NORB] = acc0.y;
    bpp[base + 2 * NORB] = acc1.x;
    bpp[base + 3 * NORB] = acc1.y;
    bpp[base + 4 * NORB] = acc2.x;
    bpp[base + 5 * NORB] = acc2.y;
    bpp[base + 6 * NORB] = acc3.x;
    bpp[base + 7 * NORB] = acc3.y;
}

template <int NSPLIT>
__global__ __launch_bounds__(256) void combine4_k(const float* __restrict__ x,
                                                  const float* __restrict__ bpp,
                                                  float* __restrict__ out) {
    int tid = blockIdx.x * blockDim.x + threadIdx.x;
    if (tid >= NB * NPIX) return;
    int i = tid % NN;
    int j = (tid / NN) % NN;
    int b = tid / NPIX;
    int k, ri, rj;
    if (j < 160) {
        if (i < 160) { k = 0; ri = i;       rj = j;       }
        else         { k = 1; ri = j;       rj = 319 - i; }
    } else {
        if (i >= 160){ k = 2; ri = 319 - i; rj = 319 - j; }
        else         { k = 3; ri = 319 - j; rj = i;       }
    }
    int off = (k * 2 + b) * NORB + orb_swizzle(ri, rj);
    float s = x[tid];
#pragma unroll
    for (int sp = 0; sp < NSPLIT; ++sp) s += bpp[sp * 8 * NORB + off];
    out[tid] = s;
}

// ---------------------------------------------------------------------------
// Fallback kernels (round-7 proven, fully exact)
// ---------------------------------------------------------------------------
template <bool USE_TAB>
__global__ __launch_bounds__(256) void residual_k(const float* __restrict__ x,
                                                  const float* __restrict__ p,
                                                  void* __restrict__ tabv) {
    int tid = blockIdx.x * blockDim.x + threadIdx.x;
    if (tid >= NRAY) return;
    int d = tid % DET_N, a = tid / DET_N;
    double beta = (double)a * (M_PI / 180.0);
    double cbd = cos(beta), sbd = sin(beta);
    double u = ((double)d - 223.5) * 1.6;
    double inorm = 1.0 / sqrt(1.0e6 + u * u);
    float dirx = (float)((-1000.0 * cbd - u * sbd) * inorm);
    float diry = (float)((-1000.0 * sbd + u * cbd) * inorm);
    float sx = (float)(500.0 * cbd + 159.5);
    float sy = (float)(500.0 * sbd + 159.5);
    const float* __restrict__ v0 = x;
    const float* __restrict__ v1 = x + NPIX;
    float acc0 = 0.0f, acc1 = 0.0f;
    for (int s = 0; s < NSAMP; ++s) {
        float t  = fmaf((float)s, DTF, T0F);
        float ix = fmaf(t, dirx, sx);
        float iy = fmaf(t, diry, sy);
        float xf = floorf(ix), yf = floorf(iy);
        int x0 = (int)xf, y0 = (int)yf;
        if (x0 < -1 || x0 >= NN || y0 < -1 || y0 >= NN) continue;
        float fx = ix - xf, fy = iy - yf;
        int x1 = x0 + 1, y1 = y0 + 1;
        bool vx0 = (x0 >= 0), vx1 = (x1 < NN);
        bool vy0 = (y0 >= 0), vy1 = (y1 < NN);
        int x0c = vx0 ? x0 : 0, x1c = vx1 ? x1 : NN - 1;
        int y0c = vy0 ? y0 : 0, y1c = vy1 ? y1 : NN - 1;
        int i00 = y0c * NN + x0c, i01 = y0c * NN + x1c;
        int i10 = y1c * NN + x0c, i11 = y1c * NN + x1c;
        float gx = 1.0f - fx, gy = 1.0f - fy;
        float w00 = (vx0 && vy0) ? gx * gy : 0.0f;
        float w01 = (vx1 && vy0) ? fx * gy : 0.0f;
        float w10 = (vx0 && vy1) ? gx * fy : 0.0f;
        float w11 = (vx1 && vy1) ? fx * fy : 0.0f;
        acc0 = fmaf(v0[i00], w00, acc0); acc0 = fmaf(v0[i01], w01, acc0);
        acc0 = fmaf(v0[i10], w10, acc0); acc0 = fmaf(v0[i11], w11, acc0);
        acc1 = fmaf(v1[i00], w00, acc1); acc1 = fmaf(v1[i01], w01, acc1);
        acc1 = fmaf(v1[i10], w10, acc1); acc1 = fmaf(v1[i11], w11, acc1);
    }
    float rv0 = -fmaf(acc0, DTF, -p[tid]) * DTF;
    float rv1 = -fmaf(acc1, DTF, -p[NRAY + tid]) * DTF;
    if constexpr (USE_TAB) {
        ((float4*)tabv)[tid] = make_float4(dirx, diry, rv0, rv1);
    } else {
        ((float2*)tabv)[tid] = make_float2(rv0, rv1);
    }
}

template <int NSPLIT, bool DIRECT, bool USE_TAB>
__global__ __launch_bounds__(256) void bp_k(const void* __restrict__ tabv,
                                            const float* __restrict__ x,
                                            float* __restrict__ outp) {
    __shared__ float4 ang[A_NUM];
    for (int a = threadIdx.x; a < A_NUM; a += blockDim.x) {
        double beta = (double)a * (M_PI / 180.0);
        double cbd = cos(beta), sbd = sin(beta);
        ang[a] = make_float4((float)cbd, (float)sbd,
                             (float)(500.0 * cbd + 159.5),
                             (float)(500.0 * sbd + 159.5));
    }
    __syncthreads();

    int tid = blockIdx.x * blockDim.x + threadIdx.x;
    if (tid >= NPIX * NSPLIT) return;
    int pix = tid % NPIX;
    int sp  = tid / NPIX;
    float fi = (float)(pix % NN), fj = (float)(pix / NN);

    float acc0 = 0.0f, acc1 = 0.0f;

    for (int a = sp; a < A_NUM; a += NSPLIT) {
        float4 A = ang[a];
        float rx = fi - A.z, ry = fj - A.w;
        float rpar  = -fmaf(rx, A.x, ry * A.y);
        float rperp = fmaf(ry, A.x, -rx * A.y);
        float us = 1000.0f * rperp * __builtin_amdgcn_rcpf(rpar);
        float dstar = fmaf(us, 0.625f, 223.5f);
        float r2 = fmaf(rx, rx, ry * ry);
        float kk = fmaf(us, us, 1.0e6f) * rsqrtf(r2);
        float dd = fmaf(kk, 8.8394e-4f, 0.05f);
        int dlo = (int)ceilf(dstar - dd);  if (dlo < 0) dlo = 0;
        int dhi = (int)floorf(dstar + dd); if (dhi > DET_N - 1) dhi = DET_N - 1;

        const float4* __restrict__ Trow =
            USE_TAB ? ((const float4*)tabv) + a * DET_N : nullptr;
        const float2* __restrict__ RVrow =
            USE_TAB ? nullptr : ((const float2*)tabv) + a * DET_N;

        for (int d = dlo; d <= dhi; ++d) {
            float dirx, diry, rv0, rv1;
            if constexpr (USE_TAB) {
                float4 T = Trow[d];
                dirx = T.x; diry = T.y; rv0 = T.z; rv1 = T.w;
            } else {
                float u = ((float)d - 223.5f) * 1.6f;
                float inv = rsqrtf(fmaf(u, u, 1.0e6f));
                dirx = fmaf(-1000.0f, A.x, -u * A.y) * inv;
                diry = fmaf(-1000.0f, A.y,  u * A.x) * inv;
                float2 RV = RVrow[d];
                rv0 = RV.x; rv1 = RV.y;
            }
            float ts = fmaf(rx, dirx, ry * diry);
            float sf = ceilf(fmaf(ts, INVDT, K0F));
            sf = fminf(fmaxf(sf, 0.0f), (float)(NSAMP - 3));
            float tt = fmaf(sf, DTF, T0F);
            float dx = fmaf(tt, dirx, -rx);
            float dy = fmaf(tt, diry, -ry);
            float ddx = DTF * dirx, ddy = DTF * diry;
#pragma unroll
            for (int k = 0; k < 3; ++k) {
                float wx = fmaxf(1.0f - fabsf(dx), 0.0f);
                float wy = fmaxf(1.0f - fabsf(dy), 0.0f);
                float w = wx * wy;
                acc0 = fmaf(w, rv0, acc0);
                acc1 = fmaf(w, rv1, acc1);
                dx += ddx; dy += ddy;
            }
        }
    }

    if constexpr (DIRECT) {
        outp[pix]        = x[pix]        + acc0;
        outp[NPIX + pix] = x[NPIX + pix] + acc1;
    } else {
        outp[(sp * 2 + 0) * NPIX + pix] = acc0;
        outp[(sp * 2 + 1) * NPIX + pix] = acc1;
    }
}

template <int NSPLIT>
__global__ __launch_bounds__(256) void combine_k(const float* __restrict__ x,
                                                 const float* __restrict__ part,
                                                 float* __restrict__ out) {
    int tid = blockIdx.x * blockDim.x + threadIdx.x;
    if (tid >= NB * NPIX) return;
    int pix = tid % NPIX, b = tid / NPIX;
    float s = x[tid];
#pragma unroll
    for (int sp = 0; sp < NSPLIT; ++sp) s += part[(sp * 2 + b) * NPIX + pix];
    out[tid] = s;
}

extern "C" void kernel_launch(void* const* d_in, const int* in_sizes, int n_in,
                              void* d_out, int out_size, void* d_ws, size_t ws_size,
                              hipStream_t stream) {
    const float* x = (const float*)d_in[0];   // [2,320,320]
    const float* p = (const float*)d_in[1];   // [2,360,448]
    float* out = (float*)d_out;               // [2,320,320]
    char* ws = (char*)d_ws;

    // Layout (bytes):
    //  dirq @ 0          (  645,120)  prep..bp4 (float4)
    //  tabD @ 645,120    (1,290,240)  prep..partial   } same region
    //  rvq  @ 645,120    (1,290,240)  finalize4..bp4  } (sequential lifetimes)
    //  tabS @ 1,935,360  (    8,192)
    //  angG @ 1,943,552  (    8,192)  prep..bp4
    //  xqb  @ 1,951,744  (1,679,616)  interleave..partial  (PN^2 uint4 fp16)
    //  xqbT @ 3,631,360  (1,679,616)  interleave..partial
    //  fpart@ 5,310,976  (5,160,960)  partial..finalize4   -> end 10,471,936
    //  bpp  @ 1,951,744  (NSPLIT*8*NORB*4) bp4..combine4 (over dead xqb/xqbT/fpart)
    const size_t bpp15_bytes = (size_t)NSPQ15 * 8 * NORB * 4; // 12.29 MB
    const size_t bpp12_bytes = (size_t)NSPQ12 * 8 * NORB * 4; // 9.83 MB
    const size_t NEED15 = 1951744 + bpp15_bytes;              // 14,239,744 (r4 proven)
    const size_t NEED12 = 1951744 + bpp12_bytes;              // 11,782,144
    const size_t NEED8  = 10471936;

    const size_t tab_bytes  = sizeof(float4) * NRAY;           // 2.58 MB
    const size_t bpp4_bytes = sizeof(float) * 8 * NPIX;        // 3.28 MB

    if (ws_size >= NEED12 || ws_size >= NEED8) {
        float4* dirq  = (float4*)(ws + 0);
        float2* tabD  = (float2*)(ws + 645120);
        float4* rvq   = (float4*)(ws + 645120);
        float4* tabS  = (float4*)(ws + 1935360);
        float4* angG  = (float4*)(ws + 1943552);
        uint4*  xqb   = (uint4*)(ws + 1951744);
        uint4*  xqbT  = (uint4*)(ws + 3631360);
        float2* fpart = (float2*)(ws + 5310976);
        float*  bpp   = (float*)(ws + 1951744);

        prep_k<<<NRAY / 256, 256, 0, stream>>>(tabD, tabS, dirq, angG);
        interleaveQB_k<<<(PN * PN + 255) / 256, 256, 0, stream>>>(x, xqb);
        interleaveQBT_k<<<(PN * PN + 255) / 256, 256, 0, stream>>>(x, xqbT);
        partial_k<<<(NRAY * NCH) / 256, 256, 0, stream>>>(tabD, tabS, xqb, xqbT, fpart);
        finalize4_k<<<(90 * DET_N + 255) / 256, 256, 0, stream>>>(p, fpart, rvq);
        if (ws_size >= NEED15) {
            bp4_k<NSPQ15><<<(NORB * NSPQ15) / 256, 256, 0, stream>>>(dirq, rvq, angG, bpp);
            combine4_k<NSPQ15><<<(NB * NPIX) / 256, 256, 0, stream>>>(x, bpp, out);
        } else if (ws_size >= NEED12) {
            bp4_k<NSPQ12><<<(NORB * NSPQ12) / 256, 256, 0, stream>>>(dirq, rvq, angG, bpp);
            combine4_k<NSPQ12><<<(NB * NPIX) / 256, 256, 0, stream>>>(x, bpp, out);
        } else {
            bp4_k<8><<<(NORB * 8) / 256, 256, 0, stream>>>(dirq, rvq, angG, bpp);
            combine4_k<8><<<(NB * NPIX) / 256, 256, 0, stream>>>(x, bpp, out);
        }
    } else if (ws_size >= tab_bytes + bpp4_bytes) {
        float4* tab = (float4*)ws;
        float* bpp  = (float*)(ws + tab_bytes);
        residual_k<true><<<(NRAY + 255) / 256, 256, 0, stream>>>(x, p, tab);
        bp_k<4, false, true><<<(NPIX * 4) / 256, 256, 0, stream>>>(tab, x, bpp);
        combine_k<4><<<(NB * NPIX + 255) / 256, 256, 0, stream>>>(x, bpp, out);
    } else if (ws_size >= tab_bytes) {
        float4* tab = (float4*)ws;
        residual_k<true><<<(NRAY + 255) / 256, 256, 0, stream>>>(x, p, tab);
        bp_k<1, true, true><<<NPIX / 256, 256, 0, stream>>>(tab, x, out);
    } else {
        float2* rw2 = (float2*)ws;
        residual_k<false><<<(NRAY + 255) / 256, 256, 0, stream>>>(x, p, rw2);
        bp_k<1, true, false><<<NPIX / 256, 256, 0, stream>>>(rw2, x, out);
    }
}